// Round 1
// baseline (186.659 us; speedup 1.0000x reference)
//
#include <hip/hip_runtime.h>
#include <hip/hip_bf16.h>

#define N 8192
#define FIN 256
#define FOUT 128
#define ALPHA 0.2f

typedef unsigned short ushort_t;
typedef __attribute__((ext_vector_type(8))) short short8;
typedef __attribute__((ext_vector_type(4))) float f32x4;

__device__ __forceinline__ ushort_t f2bf(float x) {
  union { float f; unsigned u; } v;
  v.f = x;
  unsigned r = (v.u + 0x7FFFu + ((v.u >> 16) & 1u)) >> 16;  // RNE
  return (ushort_t)r;
}

// ---------------- Kernel 1: h = X@W (fp32), s1 = h@a1, s2 = h@a2, hT = bf16(h)^T ----
__global__ __launch_bounds__(256) void k_h(const float* __restrict__ inp,
                                           const float* __restrict__ Wm,
                                           const float* __restrict__ av,
                                           ushort_t* __restrict__ hT,
                                           float* __restrict__ s1,
                                           float* __restrict__ s2) {
  __shared__ float in_lds[16][FIN];    // 16 KB
  __shared__ float h_tile[16][FOUT];   // 8 KB
  const int t = threadIdx.x;
  const int r0 = blockIdx.x * 16;

  for (int idx = t; idx < 16 * FIN; idx += 256) {
    int ii = idx >> 8, kk = idx & 255;
    in_lds[ii][kk] = inp[(size_t)(r0 + ii) * FIN + kk];
  }
  __syncthreads();

  const int c2 = (t & 63) * 2;  // column pair
  const int rg = t >> 6;        // row group: rows rg*4 .. rg*4+3
  float acc[4][2] = {};
  for (int k = 0; k < FIN; k += 4) {
    float4 iv[4];
#pragma unroll
    for (int q = 0; q < 4; ++q)
      iv[q] = *reinterpret_cast<const float4*>(&in_lds[rg * 4 + q][k]);
#pragma unroll
    for (int kk = 0; kk < 4; ++kk) {
      float2 wp = *reinterpret_cast<const float2*>(&Wm[(size_t)(k + kk) * FOUT + c2]);
#pragma unroll
      for (int q = 0; q < 4; ++q) {
        float x = reinterpret_cast<const float*>(&iv[q])[kk];
        acc[q][0] = fmaf(x, wp.x, acc[q][0]);
        acc[q][1] = fmaf(x, wp.y, acc[q][1]);
      }
    }
  }
#pragma unroll
  for (int q = 0; q < 4; ++q) {
    h_tile[rg * 4 + q][c2] = acc[q][0];
    h_tile[rg * 4 + q][c2 + 1] = acc[q][1];
  }
  __syncthreads();

  // s1/s2: wave w reduces rows 4w..4w+3 over 128 cols
  const int wv_ = t >> 6, lane = t & 63;
#pragma unroll
  for (int rr = 0; rr < 4; ++rr) {
    int row = wv_ * 4 + rr;
    float h0 = h_tile[row][lane], h1 = h_tile[row][lane + 64];
    float p1 = h0 * av[lane] + h1 * av[lane + 64];
    float p2 = h0 * av[FOUT + lane] + h1 * av[FOUT + lane + 64];
#pragma unroll
    for (int m = 32; m; m >>= 1) {
      p1 += __shfl_xor(p1, m);
      p2 += __shfl_xor(p2, m);
    }
    if (lane == 0) { s1[r0 + row] = p1; s2[r0 + row] = p2; }
  }

  // hT[c][r] = bf16(h[r][c])
  for (int idx = t; idx < 16 * FOUT; idx += 256) {
    int c = idx >> 4, ii = idx & 15;
    hT[(size_t)c * N + r0 + ii] = f2bf(h_tile[ii][c]);
  }
}

// ---------------- Kernel 1b: global max of s2 -------------------------------------
__global__ __launch_bounds__(256) void k_smax(const float* __restrict__ s2,
                                              float* __restrict__ outm) {
  __shared__ float red[4];
  const int t = threadIdx.x;
  float m = -1e30f;
  for (int i = t; i < N; i += 256) m = fmaxf(m, s2[i]);
#pragma unroll
  for (int d = 32; d; d >>= 1) m = fmaxf(m, __shfl_xor(m, d));
  if ((t & 63) == 0) red[t >> 6] = m;
  __syncthreads();
  if (t == 0) outm[0] = fmaxf(fmaxf(red[0], red[1]), fmaxf(red[2], red[3]));
}

// ---------------- Kernel 2: masked softmax + P@h (MFMA) + ELU ---------------------
// 512 blocks x 512 threads (8 waves). Block owns 16 rows x 128 cols of output.
// j-tile = 128 per iteration (64 iterations).
__global__ __launch_bounds__(512) void k_attn(const int* __restrict__ adj,
                                              const ushort_t* __restrict__ hT,
                                              const float* __restrict__ s1g,
                                              const float* __restrict__ s2g,
                                              const float* __restrict__ s2max,
                                              float* __restrict__ out) {
  __shared__ ushort_t P[2][16][128];  // 8 KB, XOR-swizzled: elem (ii,jj) at jj^((ii&7)<<3)
  __shared__ float s1s[16], ms[16], dsum[16];
  const int t = threadIdx.x;
  const int i0 = blockIdx.x * 16;

  if (t < 16) {
    float s1v = s1g[i0 + t];
    float pre = s1v + s2max[0];
    s1s[t] = s1v;
    ms[t] = pre > 0.f ? pre : ALPHA * pre;  // m~_i >= max_j e_ij (leakyrelu monotone)
  }
  __syncthreads();

  // Phase-A mapping: thread t -> row ii, j-quad jj4
  const int ii = t >> 5;
  const int jj4 = (t & 31) * 4;
  const float s1v = s1s[ii];
  const float mv = ms[ii];

  // Phase-B mapping: wave wid owns cols [16*wid, 16*wid+16)
  const int lane = t & 63;
  const int wid = t >> 6;
  const ushort_t* bptr = hT + (size_t)(wid * 16 + (lane & 15)) * N + 8 * (lane >> 4);
  const int arow = lane & 15;                       // A-frag row
  const int asw = (arow & 7) << 3;                  // A-frag swizzle
  const int akof = 8 * (lane >> 4);                 // A-frag k offset within 32-block

  const int* adjp = adj + (size_t)(i0 + ii) * N + jj4;
  int4 av = *reinterpret_cast<const int4*>(adjp);
  float4 sv = *reinterpret_cast<const float4*>(s2g + jj4);

  f32x4 acc = {0.f, 0.f, 0.f, 0.f};
  float dacc = 0.f;

  for (int it = 0; it < 64; ++it) {
    const int j0 = it * 128;
    const int buf = it & 1;

    // ---- Phase A: compute 4 attention weights, store bf16 to LDS ----
    {
      const int* ai = reinterpret_cast<const int*>(&av);
      const float* sf = reinterpret_cast<const float*>(&sv);
      ushort4 pv;
      float w;
      float pre, ee;
      pre = s1v + sf[0]; ee = pre > 0.f ? pre : ALPHA * pre;
      w = (ai[0] > 0) ? __expf(ee - mv) : 0.f; dacc += w; pv.x = f2bf(w);
      pre = s1v + sf[1]; ee = pre > 0.f ? pre : ALPHA * pre;
      w = (ai[1] > 0) ? __expf(ee - mv) : 0.f; dacc += w; pv.y = f2bf(w);
      pre = s1v + sf[2]; ee = pre > 0.f ? pre : ALPHA * pre;
      w = (ai[2] > 0) ? __expf(ee - mv) : 0.f; dacc += w; pv.z = f2bf(w);
      pre = s1v + sf[3]; ee = pre > 0.f ? pre : ALPHA * pre;
      w = (ai[3] > 0) ? __expf(ee - mv) : 0.f; dacc += w; pv.w = f2bf(w);
      *reinterpret_cast<ushort4*>(&P[buf][ii][jj4 ^ ((ii & 7) << 3)]) = pv;
    }
    __syncthreads();

    // ---- prefetch next tile's adj / s2 (hide HBM latency under MFMAs) ----
    if (it < 63) {
      av = *reinterpret_cast<const int4*>(adjp + (it + 1) * 128);
      sv = *reinterpret_cast<const float4*>(s2g + (it + 1) * 128 + jj4);
    }

    // ---- Phase B: 4 MFMAs (K=32 each) over the 128-j tile ----
#pragma unroll
    for (int kq = 0; kq < 4; ++kq) {
      int kof = kq * 32 + akof;
      short8 af = *reinterpret_cast<const short8*>(&P[buf][arow][kof ^ asw]);
      short8 bf = *reinterpret_cast<const short8*>(bptr + j0 + kq * 32);
      acc = __builtin_amdgcn_mfma_f32_16x16x32_bf16(af, bf, acc, 0, 0, 0);
    }
  }

  // ---- denominator: reduce dacc over the 32 threads sharing row ii ----
#pragma unroll
  for (int m = 16; m; m >>= 1) dacc += __shfl_xor(dacc, m);
  if ((t & 31) == 0) dsum[t >> 5] = dacc;
  __syncthreads();

  // ---- epilogue: C/D layout col=lane&15, row=(lane>>4)*4+reg (m89-verified) ----
  const int col = wid * 16 + (lane & 15);
  const int rbase = (lane >> 4) * 4;
#pragma unroll
  for (int r = 0; r < 4; ++r) {
    int row = rbase + r;
    float v = acc[r] / dsum[row];
    out[(size_t)(i0 + row) * FOUT + col] = v > 0.f ? v : (__expf(v) - 1.f);
  }
}

extern "C" void kernel_launch(void* const* d_in, const int* in_sizes, int n_in,
                              void* d_out, int out_size, void* d_ws, size_t ws_size,
                              hipStream_t stream) {
  const float* inp = (const float*)d_in[0];   // [N][FIN] fp32
  const int* adj   = (const int*)d_in[1];     // [N][N] int32
  const float* Wm  = (const float*)d_in[2];   // [FIN][FOUT] fp32
  const float* av  = (const float*)d_in[3];   // [2*FOUT] fp32
  float* out = (float*)d_out;

  // workspace carve-up
  char* ws = (char*)d_ws;
  ushort_t* hT = (ushort_t*)ws;                              // 128*8192*2 = 2 MB
  float* s1    = (float*)(ws + (size_t)FOUT * N * 2);        // 32 KB
  float* s2    = s1 + N;                                     // 32 KB
  float* s2mx  = s2 + N;                                     // 4 B

  k_h<<<N / 16, 256, 0, stream>>>(inp, Wm, av, hT, s1, s2);
  k_smax<<<1, 256, 0, stream>>>(s2, s2mx);
  k_attn<<<N / 16, 512, 0, stream>>>(adj, hT, s1, s2, s2mx, out);
}